// Round 6
// baseline (143.200 us; speedup 1.0000x reference)
//
#include <hip/hip_runtime.h>

#define GAT_H 12
#define GAT_N 4096
#define GAT_F 64
#define LOG2E 1.4426950408889634f

// ---------------------------------------------------------------------------
// Algebra: with q = log2e*(x_i*s_h + x_j*d_h),
//   exp2(lrelu(q)) = max(exp2(q), exp2(0.2q)) = B1(i,h)*max(E2^5, rho(i,h)*E2)
//   where E2 = exp2(0.2*log2e*d_h*x_j)  [192 KB table, L2-resident]
//         rho = exp2(-0.8*log2e*x_i*s_h) [SGPR-pinned]
// B1 cancels in softmax. Inner loop per (i,j,h): max(E2^4,rho)*E2 -> 4 VALU.
//
// Round-4 lesson (RF = 512 regs/SIMD): 48 accumulators/wave can't fit the
// 64-reg budget of 8 waves/EU, so the allocator round-tripped them through
// AGPRs (+2 VALU per update, VALUBusy 46%). Fix is structural: 512-thread
// blocks, 8 waves = (row-pair)x(h-group)x(j-half) -> 24 accumulators/wave,
// no software prefetch (8 waves of TLP hide L2 latency). Live set ~70 VGPR.
// ---------------------------------------------------------------------------

__device__ float g_tab2[GAT_H * GAT_N];   // 192 KB: E2 table
__device__ float g_sd[2 * GAT_H + 1];     // s[12], d[12], mean(x)

__global__ __launch_bounds__(256) void gat_prep(const float* __restrict__ W,
                                                const float* __restrict__ a,
                                                const float* __restrict__ x) {
    const int b    = blockIdx.x;
    const int tid  = threadIdx.x;
    const int lane = tid & 63;
    const int wave = tid >> 6;

    if (b < GAT_H) {                       // s_h, d_h (wave 0 only)
        if (wave == 0) {
            const float wf = W[b * GAT_F + lane];
            float ps = wf * a[b * 2 * GAT_F + lane];
            float pd = wf * a[b * 2 * GAT_F + GAT_F + lane];
            #pragma unroll
            for (int off = 32; off > 0; off >>= 1) {
                ps += __shfl_xor(ps, off, 64);
                pd += __shfl_xor(pd, off, 64);
            }
            if (lane == 0) { g_sd[b] = ps; g_sd[GAT_H + b] = pd; }
        }
        return;
    }
    if (b == GAT_H) {                      // mean(x) fallback (wave 0 only)
        if (wave == 0) {
            float s = 0.0f;
            #pragma unroll
            for (int j = 0; j < GAT_N / 64; ++j) s += x[j * 64 + lane];
            #pragma unroll
            for (int off = 32; off > 0; off >>= 1) s += __shfl_xor(s, off, 64);
            if (lane == 0) g_sd[2 * GAT_H] = s * (1.0f / GAT_N);
        }
        return;
    }

    // Table blocks: bt in [0,48): h = bt>>2, 1024-wide j-chunk = bt&3.
    const int bt    = b - (GAT_H + 1);
    const int h     = bt >> 2;
    const int chunk = bt & 3;
    const float wf  = W[h * GAT_F + lane];
    float pd = wf * a[h * 2 * GAT_F + GAT_F + lane];
    #pragma unroll
    for (int off = 32; off > 0; off >>= 1) pd += __shfl_xor(pd, off, 64);
    const float dl5 = 0.2f * pd * LOG2E;
    #pragma unroll
    for (int k = 0; k < 4; ++k) {
        const int j = chunk * 1024 + k * 256 + tid;
        g_tab2[h * GAT_N + j] = __builtin_amdgcn_exp2f(dl5 * x[j]);
    }
}

// Main: 4 rows/block, 8 waves = (row-pair 0/1) x (h-group 0/1) x (j-half 0/1).
// Per wave-iter (256 j, 2 rows, 6 heads): 2 int4 adj + 6 float4 table +
// 1 LDS b128; ~16 mask + 48 recon + 192 triple VALU.
__global__ __launch_bounds__(512) void gat_main(const float* __restrict__ x,
                                                const int* __restrict__ adj,
                                                const float* __restrict__ W,
                                                float* __restrict__ out) {
    __shared__ float xs[GAT_N];
    __shared__ float rho_s[4][16];
    __shared__ float part[2][2][4][6][2];   // [jh][hg][rloc][hh][den,num]
    __shared__ float cbuf[4][GAT_H];

    const int tid  = threadIdx.x;
    const int row0 = blockIdx.x * 4;

    #pragma unroll
    for (int it = 0; it < GAT_N / (512 * 4); ++it)
        ((float4*)xs)[it * 512 + tid] = ((const float4*)x)[it * 512 + tid];
    if (tid < 64) {
        const int r = tid >> 4, hh = tid & 15;
        if (hh < GAT_H)
            rho_s[r][hh] =
                __builtin_amdgcn_exp2f(-0.8f * LOG2E * x[row0 + r] * g_sd[hh]);
    }
    __syncthreads();

    const int lane  = tid & 63;
    const int wave  = tid >> 6;          // 0..7
    const int rp    = wave >> 2;         // 0..1 row pair
    const int hg    = (wave >> 1) & 1;   // 0..1 head group
    const int jh    = wave & 1;          // 0..1 j half
    const int hbase = hg * 6;

    // rho is wave-uniform -> pin to SGPRs so the per-triple max reads SGPR.
    float rho[2][6];
    #pragma unroll
    for (int r = 0; r < 2; ++r)
        #pragma unroll
        for (int hh = 0; hh < 6; ++hh)
            rho[r][hh] = __uint_as_float(__builtin_amdgcn_readfirstlane(
                __float_as_uint(rho_s[rp * 2 + r][hbase + hh])));

    float den[2][6], num[2][6];
    #pragma unroll
    for (int r = 0; r < 2; ++r)
        #pragma unroll
        for (int hh = 0; hh < 6; ++hh) { den[r][hh] = 0.0f; num[r][hh] = 0.0f; }

    // 4 j per lane: j = jh*2048 + it*256 + 4*lane + e
    const int4*   __restrict__ a4p =
        (const int4*)(adj + (size_t)(row0 + rp * 2) * GAT_N + jh * 2048);
    const float4* __restrict__ t4 =
        (const float4*)(g_tab2 + hbase * GAT_N + jh * 2048);
    const float4* __restrict__ x4 = (const float4*)(xs + jh * 2048);

    #pragma unroll 1
    for (int it = 0; it < 8; ++it) {
        const int idx = it * 64 + lane;
        const int4   a0 = a4p[idx];
        const int4   a1 = a4p[(GAT_N / 4) + idx];
        const float4 xv = x4[idx];

        // masks: am = (float)adj (adj in {0,1}), axj = am * x_j
        const int*   ai0 = (const int*)&a0;
        const int*   ai1 = (const int*)&a1;
        const float* xp  = (const float*)&xv;
        float am[2][4], axj[2][4];
        #pragma unroll
        for (int e = 0; e < 4; ++e) {
            am[0][e]  = (float)ai0[e];
            am[1][e]  = (float)ai1[e];
            axj[0][e] = am[0][e] * xp[e];
            axj[1][e] = am[1][e] * xp[e];
        }

        #pragma unroll
        for (int hh = 0; hh < 6; ++hh) {
            const float4 e2v = t4[hh * (GAT_N / 4) + idx];
            const float* e2  = (const float*)&e2v;
            #pragma unroll
            for (int e = 0; e < 4; ++e) {
                const float w  = e2[e] * e2[e];
                const float w4 = w * w;                 // E2^4 (shared over rows)
                #pragma unroll
                for (int r = 0; r < 2; ++r) {
                    const float p = fmaxf(w4, rho[r][hh]) * e2[e];  // max(E1,rho*E2)
                    den[r][hh] = fmaf(p, am[r][e],  den[r][hh]);
                    num[r][hh] = fmaf(p, axj[r][e], num[r][hh]);
                }
            }
        }
    }

    #pragma unroll
    for (int r = 0; r < 2; ++r) {
        #pragma unroll
        for (int hh = 0; hh < 6; ++hh) {
            float d = den[r][hh], n = num[r][hh];
            #pragma unroll
            for (int off = 32; off > 0; off >>= 1) {
                d += __shfl_xor(d, off, 64);
                n += __shfl_xor(n, off, 64);
            }
            if (lane == 0) {
                part[jh][hg][rp * 2 + r][hh][0] = d;
                part[jh][hg][rp * 2 + r][hh][1] = n;
            }
        }
    }
    __syncthreads();

    if (tid < 64) {
        const int r = tid >> 4, h = tid & 15;
        if (h < GAT_H) {
            const int g  = (h >= 6) ? 1 : 0;
            const int hh = h - 6 * g;
            const float dsum = part[0][g][r][hh][0] + part[1][g][r][hh][0];
            const float nsum = part[0][g][r][hh][1] + part[1][g][r][hh][1];
            cbuf[r][h] = dsum > 0.0f ? nsum / dsum : g_sd[2 * GAT_H];
        }
    }
    __syncthreads();

    // Epilogue: out[row][h*64+f] = c[row][h] * W[h*64+f]; pos == h*64+f.
    #pragma unroll
    for (int r = 0; r < 4; ++r) {
        const size_t base = (size_t)(row0 + r) * (GAT_H * GAT_F);
        #pragma unroll
        for (int k = 0; k < 2; ++k) {
            const int pos = k * 512 + tid;
            if (pos < GAT_H * GAT_F)
                out[base + pos] = cbuf[r][pos >> 6] * W[pos];
        }
    }
}

extern "C" void kernel_launch(void* const* d_in, const int* in_sizes, int n_in,
                              void* d_out, int out_size, void* d_ws, size_t ws_size,
                              hipStream_t stream) {
    const float* x   = (const float*)d_in[0];
    const int*   adj = (const int*)d_in[1];
    const float* W   = (const float*)d_in[2];
    const float* a   = (const float*)d_in[3];
    float* out = (float*)d_out;
    (void)d_ws; (void)ws_size;   // all scratch is static __device__ memory

    gat_prep<<<GAT_H + 1 + 48, 256, 0, stream>>>(W, a, x);
    gat_main<<<GAT_N / 4, 512, 0, stream>>>(x, adj, W, out);
}

// Round 7
// 135.390 us; speedup vs baseline: 1.0577x; 1.0577x over previous
//
#include <hip/hip_runtime.h>

#define GAT_H 12
#define GAT_N 4096
#define GAT_F 64
#define LOG2E 1.4426950408889634f

// ---------------------------------------------------------------------------
// Algebra: with q = x_i*s_h + x_j*d_h,
//   exp(lrelu(q)) = B1(i,h) * max(E2^5, rho(i,h)*E2) = B1 * max(E2^4, rho)*E2
//   where E2  = exp2(0.2*log2e*d_h*x_j)   [192 KB table]
//         rho = exp2(-0.8*log2e*x_i*s_h)  [6 SGPRs/wave]
// B1 cancels in softmax. Inner loop per (i,j,h): 2 shared sq + max+mul+2 fma.
//
// Round-5 lesson: latency, not pressure, is now the limit (VALUBusy 39%,
// ~1400 cyc exposed/iter with no prefetch). Round-6 structure:
//   8 waves = row(4) x head-group(2); 1 row x 6 heads/wave -> 12 accums.
//   Table slice (12 KB/iter) double-buffered in LDS: inner reads are
//   conflict-free ds_read_b128; staging loads issued at iter top, written
//   after compute (async split). adj + x prefetched one iter ahead.
//   Live set ~60 VGPR -> 8 waves/EU; 4 blocks/CU (LDS 25 KB).
// ---------------------------------------------------------------------------

__device__ float g_tab2[GAT_H * GAT_N];   // 192 KB: E2 table
__device__ float g_sd[2 * GAT_H + 1];     // s[12], d[12], mean(x)

__global__ __launch_bounds__(256) void gat_prep(const float* __restrict__ W,
                                                const float* __restrict__ a,
                                                const float* __restrict__ x) {
    const int b    = blockIdx.x;
    const int tid  = threadIdx.x;
    const int lane = tid & 63;
    const int wave = tid >> 6;

    if (b < GAT_H) {                       // s_h, d_h (wave 0 only)
        if (wave == 0) {
            const float wf = W[b * GAT_F + lane];
            float ps = wf * a[b * 2 * GAT_F + lane];
            float pd = wf * a[b * 2 * GAT_F + GAT_F + lane];
            #pragma unroll
            for (int off = 32; off > 0; off >>= 1) {
                ps += __shfl_xor(ps, off, 64);
                pd += __shfl_xor(pd, off, 64);
            }
            if (lane == 0) { g_sd[b] = ps; g_sd[GAT_H + b] = pd; }
        }
        return;
    }
    if (b == GAT_H) {                      // mean(x) fallback (wave 0 only)
        if (wave == 0) {
            float s = 0.0f;
            #pragma unroll
            for (int j = 0; j < GAT_N / 64; ++j) s += x[j * 64 + lane];
            #pragma unroll
            for (int off = 32; off > 0; off >>= 1) s += __shfl_xor(s, off, 64);
            if (lane == 0) g_sd[2 * GAT_H] = s * (1.0f / GAT_N);
        }
        return;
    }

    // Table blocks: bt in [0,48): h = bt>>2, 1024-wide j-chunk = bt&3.
    const int bt    = b - (GAT_H + 1);
    const int h     = bt >> 2;
    const int chunk = bt & 3;
    const float wf  = W[h * GAT_F + lane];
    float pd = wf * a[h * 2 * GAT_F + GAT_F + lane];
    #pragma unroll
    for (int off = 32; off > 0; off >>= 1) pd += __shfl_xor(pd, off, 64);
    const float dl5 = 0.2f * pd * LOG2E;
    #pragma unroll
    for (int k = 0; k < 4; ++k) {
        const int j = chunk * 1024 + k * 256 + tid;
        g_tab2[h * GAT_N + j] = __builtin_amdgcn_exp2f(dl5 * x[j]);
    }
}

// Main: 4 rows/block, 8 waves = row(4) x head-group(2). 16 iters of 256 j.
__global__ __launch_bounds__(512) void gat_main(const float* __restrict__ x,
                                                const int* __restrict__ adj,
                                                const float* __restrict__ W,
                                                float* __restrict__ out) {
    __shared__ float tab_lds[2][GAT_H][256];   // 24 KB, double-buffered slice
    __shared__ float cbuf[4][GAT_H];

    const int tid   = threadIdx.x;
    const int row0  = blockIdx.x * 4;
    const int lane  = tid & 63;
    const int wave  = tid >> 6;          // 0..7
    const int r     = wave >> 1;         // 0..3 row
    const int hg    = wave & 1;          // 0..1 head group
    const int hbase = hg * 6;
    const int row   = row0 + r;

    // rho (wave-uniform) -> SGPR-pinned
    const float xrow = x[row];
    float rho[6];
    #pragma unroll
    for (int hh = 0; hh < 6; ++hh)
        rho[hh] = __uint_as_float(__builtin_amdgcn_readfirstlane(__float_as_uint(
            __builtin_amdgcn_exp2f(-0.8f * LOG2E * xrow * g_sd[hbase + hh]))));

    float den[6], num[6];
    #pragma unroll
    for (int hh = 0; hh < 6; ++hh) { den[hh] = 0.0f; num[hh] = 0.0f; }

    // Staging geometry: slice = [12 heads][256 j] = 1536 float2; 3 per thread.
    // Thread t, copy k: pair p = k*512+t -> head sh[k] = p>>7, pair-in-row sj[k] = p&127.
    const float2* __restrict__ tg = (const float2*)g_tab2;   // [h][2048] pairs
    int sh[3], sj[3];
    #pragma unroll
    for (int k = 0; k < 3; ++k) {
        const int p = k * 512 + tid;
        sh[k] = p >> 7;
        sj[k] = p & 127;
    }
    float2* __restrict__ lds2 = (float2*)tab_lds;            // [2][12][128] pairs

    // Prologue: stage slice 0 into buf 0; first adj/x.
    #pragma unroll
    for (int k = 0; k < 3; ++k)
        lds2[sh[k] * 128 + sj[k]] = tg[sh[k] * (GAT_N / 2) + sj[k]];
    const int4*   __restrict__ a4p = (const int4*)(adj + (size_t)row * GAT_N);
    const float4* __restrict__ x4  = (const float4*)x;
    int4   a_c = a4p[lane];
    float4 x_c = x4[lane];
    __syncthreads();

    #pragma unroll 2
    for (int it = 0; it < 16; ++it) {
        const int buf = it & 1;                 // constant under unroll-2
        const int nit = (it < 15) ? it + 1 : 15;

        // issue next-slice global loads (consumed after compute)
        float2 st[3];
        #pragma unroll
        for (int k = 0; k < 3; ++k)
            st[k] = tg[sh[k] * (GAT_N / 2) + nit * 128 + sj[k]];
        // prefetch next adj/x
        const int ni = nit * 64 + lane;
        const int4   a_n = a4p[ni];
        const float4 x_n = x4[ni];

        // masks: am = (float)adj (adj in {0,1}), axj = am * x_j
        const int*   ai = (const int*)&a_c;
        const float* xp = (const float*)&x_c;
        float am[4], axj[4];
        #pragma unroll
        for (int e = 0; e < 4; ++e) {
            am[e]  = (float)ai[e];
            axj[e] = am[e] * xp[e];
        }

        // compute from staged slice (conflict-free ds_read_b128)
        #pragma unroll
        for (int hh = 0; hh < 6; ++hh) {
            const float4 e2v = *(const float4*)&tab_lds[buf][hbase + hh][4 * lane];
            const float* e2  = (const float*)&e2v;
            #pragma unroll
            for (int e = 0; e < 4; ++e) {
                const float w  = e2[e] * e2[e];
                const float w4 = w * w;                          // E2^4
                const float p  = fmaxf(w4, rho[hh]) * e2[e];     // max(E1, rho*E2)
                den[hh] = fmaf(p, am[e],  den[hh]);
                num[hh] = fmaf(p, axj[e], num[hh]);
            }
        }

        // write next slice to the other buffer (vmcnt inserted by compiler)
        #pragma unroll
        for (int k = 0; k < 3; ++k)
            lds2[(buf ^ 1) * (GAT_H * 128) + sh[k] * 128 + sj[k]] = st[k];
        a_c = a_n; x_c = x_n;
        __syncthreads();
    }

    // wave-level reduction; each (row, head-group) wave owns its 6 heads fully
    #pragma unroll
    for (int hh = 0; hh < 6; ++hh) {
        #pragma unroll
        for (int off = 32; off > 0; off >>= 1) {
            den[hh] += __shfl_xor(den[hh], off, 64);
            num[hh] += __shfl_xor(num[hh], off, 64);
        }
    }
    if (lane == 0) {
        const float fb = g_sd[2 * GAT_H];
        #pragma unroll
        for (int hh = 0; hh < 6; ++hh)
            cbuf[r][hbase + hh] = den[hh] > 0.0f ? num[hh] / den[hh] : fb;
    }
    __syncthreads();

    // Epilogue: out[row][h*64+f] = c[row][h] * W[h*64+f]; pos == h*64+f.
    #pragma unroll
    for (int rr = 0; rr < 4; ++rr) {
        const size_t base = (size_t)(row0 + rr) * (GAT_H * GAT_F);
        #pragma unroll
        for (int k = 0; k < 2; ++k) {
            const int pos = k * 512 + tid;
            if (pos < GAT_H * GAT_F)
                out[base + pos] = cbuf[rr][pos >> 6] * W[pos];
        }
    }
}

extern "C" void kernel_launch(void* const* d_in, const int* in_sizes, int n_in,
                              void* d_out, int out_size, void* d_ws, size_t ws_size,
                              hipStream_t stream) {
    const float* x   = (const float*)d_in[0];
    const int*   adj = (const int*)d_in[1];
    const float* W   = (const float*)d_in[2];
    const float* a   = (const float*)d_in[3];
    float* out = (float*)d_out;
    (void)d_ws; (void)ws_size;   // all scratch is static __device__ memory

    gat_prep<<<GAT_H + 1 + 48, 256, 0, stream>>>(W, a, x);
    gat_main<<<GAT_N / 4, 512, 0, stream>>>(x, adj, W, out);
}